// Round 2
// baseline (655.971 us; speedup 1.0000x reference)
//
#include <hip/hip_runtime.h>
#include <cstdint>
#include <cstddef>

typedef __bf16 bf16_t;
typedef __bf16 bf16x8 __attribute__((ext_vector_type(8)));
typedef float  f32x4  __attribute__((ext_vector_type(4)));
typedef unsigned int uint32x4 __attribute__((ext_vector_type(4)));
typedef unsigned int uint32x2 __attribute__((ext_vector_type(2)));

#define DEV_INLINE __device__ __forceinline__

constexpr int Bsz = 4, Ssz = 2048, HID = 1024, FAC = 256, NH = 16, DKc = 64;
constexpr int Mrows = Bsz * Ssz; // 8192
constexpr float QSCALE = 0.18033688011112042f; // (1/sqrt(64)) * log2(e)

struct Ptr8 { const float* p[8]; };
struct Ptr3 { const float* p[3]; };

DEV_INLINE float fast_exp2(float x) {
#if __has_builtin(__builtin_amdgcn_exp2f)
  return __builtin_amdgcn_exp2f(x);
#else
  return exp2f(x);
#endif
}

// async global->LDS, 16 B per lane. LDS dest is wave-uniform base + lane*16.
DEV_INLINE void async16(const void* g, void* l) {
  __builtin_amdgcn_global_load_lds((const __attribute__((address_space(1))) void*)g,
                                   (__attribute__((address_space(3))) void*)l, 16, 0, 0);
}

// bank swizzle for [64][64] bf16 tiles staged by global_load_lds:
// LDS[row][c'] holds logical col16 (c' ^ SW(row)). Readers XOR too.
DEV_INLINE int SW(int r) { return (r & 3) | ((r >> 1) & 4); }

// ---------------- prep: weight transpose+cast (z<8) + bias/mask pack (z==8) ----------------
__global__ __launch_bounds__(256) void k_prep(Ptr8 w, Ptr8 bsrc, const int* __restrict__ mask,
                                              bf16_t* wpt, bf16_t* wtt,
                                              float* bp, float* bt, float* mf, bf16_t* mb) {
  const int z = blockIdx.z;
  if (z == 8) {
    const int bid = blockIdx.y * 32 + blockIdx.x;
    if (bid >= 64) return;
    const int i = bid * 256 + threadIdx.x; // 0..16383
    if (i < 4 * FAC) bp[i] = bsrc.p[i >> 8][i & 255];
    if (i < 4 * HID) bt[i] = bsrc.p[4 + (i >> 10)][i & 1023];
    if (i < Bsz * Ssz) {
      const float m = (mask[i] != 0) ? 1.f : 0.f;
      mf[i] = m;
      mb[i] = (bf16_t)m;
    }
    return;
  }
  const int K = (z < 4) ? HID : FAC;
  const int N = (z < 4) ? FAC : HID;
  if ((int)(blockIdx.x * 32) >= N || (int)(blockIdx.y * 32) >= K) return;
  __shared__ float t[32][33];
  const float* src = w.p[z];
  bf16_t* dst = (z < 4) ? (wpt + (size_t)z * FAC * HID) : (wtt + (size_t)(z - 4) * FAC * HID);
  const int tx = threadIdx.x & 31, ty = threadIdx.x >> 5;
  const int kb = blockIdx.y * 32, nb = blockIdx.x * 32;
#pragma unroll
  for (int j = 0; j < 4; ++j)
    t[ty + j * 8][tx] = src[(size_t)(kb + ty + j * 8) * N + nb + tx];
  __syncthreads();
#pragma unroll
  for (int j = 0; j < 4; ++j)
    dst[(size_t)(nb + ty + j * 8) * K + kb + tx] = (bf16_t)t[tx][ty + j * 8];
}

// ---------------- proj GEMM: C[M,256] = leaky(A[M,K] @ Bt[256,K]^T + bias) ----------------
// 64x128 tile, BK=32, 4 waves (each 64x32), double-buffered LDS, ONE barrier per K-iter.
template <int CAST_A, typename OUT_T>
__global__ __launch_bounds__(256) void k_gemmP(Ptr3 Asrc,
                                               const bf16_t* __restrict__ Aall,
                                               const bf16_t* __restrict__ Bt_,
                                               const float* __restrict__ biasAll,
                                               OUT_T* __restrict__ Call,
                                               int K,
                                               long long Az, long long Bz, long long Cz, int biasz) {
  constexpr int LDTA = CAST_A ? 40 : 32;
  __shared__ __align__(16) bf16_t As[2][64 * LDTA];
  __shared__ __align__(16) bf16_t Bs[2][128 * 32];

  const int z = blockIdx.z;
  const bf16_t* Bt = Bt_ + (size_t)z * Bz;
  const float* bias = biasAll + (size_t)z * biasz;
  OUT_T* C = Call + (size_t)z * Cz;

  const int tid = threadIdx.x;
  const int lane = tid & 63, wave = tid >> 6;
  const int quad = lane >> 4, l16 = lane & 15;
  const int m0 = blockIdx.y * 64, n0 = blockIdx.x * 128;

  const int arow = wave * 16 + (lane >> 2), akc = (lane & 3) * 8;
  const bf16_t* gB0 = Bt + (size_t)(n0 + arow) * K + akc;
  const bf16_t* gB1 = gB0 + (size_t)64 * K;

  const float* gAf = nullptr;
  const bf16_t* gA = nullptr;
  const int crow = tid >> 2, chalf = (tid & 3) * 8;
  if (CAST_A) gAf = Asrc.p[z] + (size_t)(m0 + crow) * K + chalf;
  else        gA  = Aall + (size_t)z * Az + (size_t)(m0 + arow) * K + akc;

  // prologue: stage k0=0 into buffer 0
  async16(gB0, Bs[0] + wave * 512);
  async16(gB1, Bs[0] + 2048 + wave * 512);
  if (CAST_A) {
    f32x4 x0 = *(const f32x4*)gAf;
    f32x4 x1 = *(const f32x4*)(gAf + 4);
    union { bf16_t h[8]; uint32x4 u; } o;
#pragma unroll
    for (int j = 0; j < 4; ++j) { o.h[j] = (bf16_t)x0[j]; o.h[4 + j] = (bf16_t)x1[j]; }
    *(uint32x4*)(As[0] + crow * LDTA + chalf) = o.u;
  } else {
    async16(gA, As[0] + wave * 512);
  }

  f32x4 acc[4][2] = {};
  const int nk = K / 32;

  for (int it = 0; it < nk; ++it) {
    const int cur = it & 1, nxt = cur ^ 1;
    __syncthreads();

    f32x4 xa, xb;
    const int k1 = (it + 1) * 32;
    if (it + 1 < nk) {
      async16(gB0 + k1, Bs[nxt] + wave * 512);
      async16(gB1 + k1, Bs[nxt] + 2048 + wave * 512);
      if (CAST_A) {
        xa = *(const f32x4*)(gAf + k1);
        xb = *(const f32x4*)(gAf + k1 + 4);
      } else {
        async16(gA + k1, As[nxt] + wave * 512);
      }
    }

    bf16x8 af[4], bfr[2];
#pragma unroll
    for (int i = 0; i < 4; ++i)
      af[i] = *(const bf16x8*)(As[cur] + (i * 16 + l16) * LDTA + quad * 8);
#pragma unroll
    for (int i = 0; i < 2; ++i)
      bfr[i] = *(const bf16x8*)(Bs[cur] + (wave * 32 + i * 16 + l16) * 32 + quad * 8);
#pragma unroll
    for (int mi = 0; mi < 4; ++mi)
#pragma unroll
      for (int ni = 0; ni < 2; ++ni)
        acc[mi][ni] = __builtin_amdgcn_mfma_f32_16x16x32_bf16(af[mi], bfr[ni], acc[mi][ni], 0, 0, 0);

    if (CAST_A && it + 1 < nk) {
      union { bf16_t h[8]; uint32x4 u; } o;
#pragma unroll
      for (int j = 0; j < 4; ++j) { o.h[j] = (bf16_t)xa[j]; o.h[4 + j] = (bf16_t)xb[j]; }
      *(uint32x4*)(As[nxt] + crow * LDTA + chalf) = o.u;
    }
  }

#pragma unroll
  for (int mi = 0; mi < 4; ++mi) {
    const int rbase = m0 + mi * 16 + quad * 4;
#pragma unroll
    for (int ni = 0; ni < 2; ++ni) {
      const int col = n0 + wave * 32 + ni * 16 + l16;
      const float bv = bias[col];
#pragma unroll
      for (int r = 0; r < 4; ++r) {
        float y = acc[mi][ni][r] + bv;
        y = (y > 0.f) ? y : 0.2f * y;
        C[(size_t)(rbase + r) * FAC + col] = (OUT_T)y;
      }
    }
  }
}

// ---------------- tran GEMM: C[M,N] = (A[M,K] @ Bt[N,K]^T + bias) * scale ----------------
// Double-buffered LDS, ONE barrier per K-iter (same proven structure as k_gemmP).
// TVW=1: z==2 writes masked V DIRECTLY TRANSPOSED into C2 ([b,h,d,s] layout), fusing k_tv.
template <int TVW, typename OUT_T>
__global__ __launch_bounds__(256) void k_gemm(const bf16_t* __restrict__ Aall,
                                              const bf16_t* __restrict__ Btall,
                                              const float* __restrict__ biasAll,
                                              OUT_T* __restrict__ Call,
                                              bf16_t* __restrict__ C2,
                                              const float* __restrict__ rowmul,
                                              int N, int K,
                                              long long Az, long long Bz, long long Cz, int biasz,
                                              float sc0, float sc1) {
  __shared__ __align__(16) bf16_t As[2][128 * 32];
  __shared__ __align__(16) bf16_t Bs[2][128 * 32];

  const int z = blockIdx.z;
  const bf16_t* Bt = Btall + (size_t)z * Bz;
  const float* bias = biasAll + (size_t)z * biasz;
  OUT_T* C = Call + (size_t)z * Cz;
  const float scale = (z == 0) ? sc0 : sc1;

  const int tid = threadIdx.x;
  const int lane = tid & 63, wave = tid >> 6;
  const int quad = lane >> 4, l16 = lane & 15;
  const int wr = wave >> 1, wc = wave & 1;
  const int m0 = blockIdx.y * 128, n0 = blockIdx.x * 128;

  const int arow = wave * 16 + (lane >> 2), akc = (lane & 3) * 8;
  const bf16_t* gB0 = Bt + (size_t)(n0 + arow) * K + akc;
  const bf16_t* gB1 = gB0 + (size_t)64 * K;
  const bf16_t* A = Aall + (size_t)z * Az;
  const bf16_t* gA0 = A + (size_t)(m0 + arow) * K + akc;
  const bf16_t* gA1 = gA0 + (size_t)64 * K;

  // prologue: stage k0=0 into buffer 0
  async16(gB0, Bs[0] + wave * 512);
  async16(gB1, Bs[0] + 2048 + wave * 512);
  async16(gA0, As[0] + wave * 512);
  async16(gA1, As[0] + 2048 + wave * 512);

  f32x4 acc[4][4] = {};
  const int nk = K / 32;

  for (int it = 0; it < nk; ++it) {
    const int cur = it & 1, nxt = cur ^ 1;
    __syncthreads();

    if (it + 1 < nk) {
      const int k1 = (it + 1) * 32;
      async16(gB0 + k1, Bs[nxt] + wave * 512);
      async16(gB1 + k1, Bs[nxt] + 2048 + wave * 512);
      async16(gA0 + k1, As[nxt] + wave * 512);
      async16(gA1 + k1, As[nxt] + 2048 + wave * 512);
    }

    bf16x8 af[4], bfr[4];
#pragma unroll
    for (int i = 0; i < 4; ++i)
      af[i] = *(const bf16x8*)(As[cur] + (wr * 64 + i * 16 + l16) * 32 + quad * 8);
#pragma unroll
    for (int i = 0; i < 4; ++i)
      bfr[i] = *(const bf16x8*)(Bs[cur] + (wc * 64 + i * 16 + l16) * 32 + quad * 8);
#pragma unroll
    for (int mi = 0; mi < 4; ++mi)
#pragma unroll
      for (int ni = 0; ni < 4; ++ni)
        acc[mi][ni] = __builtin_amdgcn_mfma_f32_16x16x32_bf16(af[mi], bfr[ni], acc[mi][ni], 0, 0, 0);
  }

  if (TVW && z == 2) {
    // transposed masked write: V^T[(b*NH+h)*64+d][s] = (acc + bias) * mask[s]
#pragma unroll
    for (int mi = 0; mi < 4; ++mi) {
      const int rbase = m0 + wr * 64 + mi * 16 + quad * 4;
      const int bb = rbase >> 11, s = rbase & 2047;
      float rmv[4];
#pragma unroll
      for (int r = 0; r < 4; ++r) rmv[r] = rowmul[rbase + r];
#pragma unroll
      for (int ni = 0; ni < 4; ++ni) {
        const int col = n0 + wc * 64 + ni * 16 + l16;
        const float bv = bias[col];
        const int h = col >> 6, d = col & 63;
        union { bf16_t e[4]; uint32x2 u; } p;
#pragma unroll
        for (int r = 0; r < 4; ++r) p.e[r] = (bf16_t)((acc[mi][ni][r] + bv) * rmv[r]);
        *(uint32x2*)(C2 + (((size_t)((bb * NH + h) * DKc + d)) << 11) + s) = p.u;
      }
    }
    return;
  }

#pragma unroll
  for (int mi = 0; mi < 4; ++mi) {
    const int rbase = m0 + wr * 64 + mi * 16 + quad * 4;
#pragma unroll
    for (int ni = 0; ni < 4; ++ni) {
      const int col = n0 + wc * 64 + ni * 16 + l16;
      const float bv = bias[col];
#pragma unroll
      for (int r = 0; r < 4; ++r) {
        float y = (acc[mi][ni][r] + bv) * scale;
        C[(size_t)(rbase + r) * N + col] = (OUT_T)y;
      }
    }
  }
}

// ---------------- flash attention v7: split-KV teams ----------------
// 8 waves = 2 teams x 4 waves. Each team covers HALF the 64 k-rows of the tile
// (team 0: koff {0,4}; team 1: {32,36}) but ALL 256 q-rows (4 groups x 16).
// Per-wave LDS reads drop 18 -> 9 ds_read_b128 per kt (LDS BW was 52% of wall in v6).
// Partial acc/dacc merged once at the end via a 20 KB LDS scratch.
__global__ __launch_bounds__(512, 4) void k_attn(const bf16_t* __restrict__ qkv,
                                                 const bf16_t* __restrict__ mb,
                                                 bf16_t* __restrict__ cv) {
  __shared__ __align__(16) bf16_t Ks[2][64 * 64];
  __shared__ __align__(16) bf16_t Vt[2][64 * 64];
  __shared__ __align__(16) bf16_t Ml[Ssz];
  __shared__ __align__(16) float scr[256 * 20]; // cross-team reduction scratch (per g round)

  const int qt = blockIdx.x, h = blockIdx.y, b = blockIdx.z;
  const bf16_t* qp = qkv;
  const bf16_t* kp = qkv + (size_t)Mrows * HID;
  const bf16_t* vtp = qkv + 2 * (size_t)Mrows * HID + (size_t)(b * NH + h) * DKc * Ssz;

  const int tid = threadIdx.x;
  const int lane = tid & 63, wave = tid >> 6;   // wave 0..7
  const int quad = lane >> 4, l16 = lane & 15;
  const int team = wave >> 2, w4 = wave & 3;    // 2 teams x 4 waves

  // staging: each of 8 waves stages 8 rows of K and 8 rows of V^T (1024 B each)
  const int r0 = wave * 8 + (lane >> 3);
  const int c0 = ((lane & 7) ^ SW(r0)) * 8;
  const int ldsOff = wave * 512; // elements (1024 B per wave)
  const bf16_t* kgA = kp + (size_t)(b * Ssz + r0) * HID + h * DKc + c0;
  const bf16_t* vgA = vtp + (size_t)r0 * Ssz + c0;

  *(uint32x2*)(Ml + tid * 4) = *(const uint32x2*)(mb + (size_t)b * Ssz + tid * 4);
  async16(kgA, Ks[0] + ldsOff);
  async16(vgA, Vt[0] + ldsOff);

  // each wave owns 64 q-rows (4 groups of 16); both teams load the same q
  bf16x8 aq0[4], aq1[4];
#pragma unroll
  for (int g = 0; g < 4; ++g) {
    const size_t qrow = (size_t)(b * Ssz + qt * 256 + g * 64 + w4 * 16 + l16) * HID + h * DKc + quad * 8;
    aq0[g] = *(const bf16x8*)(qp + qrow);
    aq1[g] = *(const bf16x8*)(qp + qrow + 32);
  }
  __syncthreads();

  const int krow = 8 * (l16 >> 2) + (l16 & 3);
  f32x4 acc[4][4] = {};
  f32x4 dacc[4] = {};
  const bf16x8 zfrag = {};

  for (int kt = 0; kt < 32; ++kt) {
    const int cur = kt & 1, nxt = cur ^ 1;
    if (kt < 31) {
      const size_t ko = (size_t)(kt + 1) * 64 * HID;
      const int vo = (kt + 1) * 64;
      async16(kgA + ko, Ks[nxt] + ldsOff);
      async16(vgA + vo, Vt[nxt] + ldsOff);
    }

    // QK^T over this team's 32 k-rows, all 4 q-groups
    union U { uint32x4 u; bf16x8 h; } ap[4];
#pragma unroll
    for (int ks = 0; ks < 2; ++ks) {
      const int row = krow + ks * 4 + team * 32;
      const int sw = SW(row);
      bf16x8 a0 = *(const bf16x8*)(Ks[cur] + row * 64 + (quad ^ sw) * 8);
      bf16x8 a1 = *(const bf16x8*)(Ks[cur] + row * 64 + ((quad + 4) ^ sw) * 8);
#pragma unroll
      for (int g = 0; g < 4; ++g) {
        f32x4 c = {};
        c = __builtin_amdgcn_mfma_f32_16x16x32_bf16(a0, aq0[g], c, 0, 0, 0);
        c = __builtin_amdgcn_mfma_f32_16x16x32_bf16(a1, aq1[g], c, 0, 0, 0);
        union { bf16_t h[2]; uint32_t u; } p01, p23;
        p01.h[0] = (bf16_t)fast_exp2(c[0]);
        p01.h[1] = (bf16_t)fast_exp2(c[1]);
        p23.h[0] = (bf16_t)fast_exp2(c[2]);
        p23.h[1] = (bf16_t)fast_exp2(c[3]);
        ap[g].u[ks * 2] = p01.u;
        ap[g].u[ks * 2 + 1] = p23.u;
      }
    }

    // denominator partial: P x mask (this team's k-half)
    bf16x8 mr = *(const bf16x8*)(Ml + kt * 64 + team * 32 + quad * 8);
    if (l16 != 0) mr = zfrag;
#pragma unroll
    for (int g = 0; g < 4; ++g)
      dacc[g] = __builtin_amdgcn_mfma_f32_16x16x32_bf16(ap[g].h, mr, dacc[g], 0, 0, 0);

    // PV partial over this team's k-half
#pragma unroll
    for (int d = 0; d < 4; ++d) {
      const int row = d * 16 + l16;
      const int sw = SW(row);
      bf16x8 bv = *(const bf16x8*)(Vt[cur] + row * 64 + (((quad + team * 4)) ^ sw) * 8);
#pragma unroll
      for (int g = 0; g < 4; ++g)
        acc[g][d] = __builtin_amdgcn_mfma_f32_16x16x32_bf16(ap[g].h, bv, acc[g][d], 0, 0, 0);
    }

    __syncthreads();
  }

  // cross-team reduction (team 1 -> scratch, team 0 adds + stores), one g per round
  const int sbase = (w4 * 64 + lane) * 20;
  for (int g = 0; g < 4; ++g) {
    if (team == 1) {
#pragma unroll
      for (int d = 0; d < 4; ++d) *(f32x4*)(scr + sbase + d * 4) = acc[g][d];
      *(f32x4*)(scr + sbase + 16) = dacc[g];
    }
    __syncthreads();
    if (team == 0) {
#pragma unroll
      for (int d = 0; d < 4; ++d) acc[g][d] += *(const f32x4*)(scr + sbase + d * 4);
      dacc[g] += *(const f32x4*)(scr + sbase + 16);
      const size_t obase = (size_t)(b * Ssz + qt * 256 + g * 64 + w4 * 16 + quad * 4) * HID + h * DKc + l16;
#pragma unroll
      for (int r = 0; r < 4; ++r) {
        const float denom = __shfl(dacc[g][r], lane & 48, 64);
        const float rl = 1.f / denom;
#pragma unroll
        for (int d = 0; d < 4; ++d)
          cv[obase + (size_t)r * HID + d * 16] = (bf16_t)(acc[g][d][r] * rl);
      }
    }
    __syncthreads();
  }
}

// ---------------- host ----------------
extern "C" void kernel_launch(void* const* d_in, const int* in_sizes, int n_in,
                              void* d_out, int out_size, void* d_ws, size_t ws_size,
                              hipStream_t stream) {
  (void)in_sizes; (void)n_in; (void)out_size; (void)ws_size;
  const float* q_in = (const float*)d_in[0];
  const float* k_in = (const float*)d_in[1];
  const float* v_in = (const float*)d_in[2];
  const int* mask = (const int*)d_in[3];

  bf16_t* XB = (bf16_t*)d_ws;                          // 3 slots [8192,1024] bf16: q, k, V^T
  bf16_t* H3 = XB + (size_t)3 * Mrows * HID;           // 3 x [8192,256] bf16
  bf16_t* CV = H3 + (size_t)3 * Mrows * FAC;           // [8192,1024] bf16 (attn out)
  bf16_t* WPT = CV + (size_t)Mrows * HID;              // 4 x [256,1024] bf16
  bf16_t* WTT = WPT + (size_t)4 * FAC * HID;           // 4 x [1024,256] bf16
  float* BP = (float*)(WTT + (size_t)4 * FAC * HID);   // 4 x 256 f32
  float* BT = BP + 4 * FAC;                            // 4 x 1024 f32
  float* MF = BT + 4 * HID;                            // [8192] f32 mask rowmul
  bf16_t* MB = (bf16_t*)(MF + Mrows);                  // [8192] bf16 mask row
  bf16_t* VTg = XB + 2 * (size_t)Mrows * HID;          // V^T slot

  Ptr8 w;
  w.p[0] = (const float*)d_in[4];  w.p[1] = (const float*)d_in[8];
  w.p[2] = (const float*)d_in[12]; w.p[3] = (const float*)d_in[16];
  w.p[4] = (const float*)d_in[6];  w.p[5] = (const float*)d_in[10];
  w.p[6] = (const float*)d_in[14]; w.p[7] = (const float*)d_in[18];
  Ptr8 bs;
  bs.p[0] = (const float*)d_in[5];  bs.p[1] = (const float*)d_in[9];
  bs.p[2] = (const float*)d_in[13]; bs.p[3] = (const float*)d_in[17];
  bs.p[4] = (const float*)d_in[7];  bs.p[5] = (const float*)d_in[11];
  bs.p[6] = (const float*)d_in[15]; bs.p[7] = (const float*)d_in[19];
  hipLaunchKernelGGL(k_prep, dim3(32, 32, 9), dim3(256), 0, stream, w, bs, mask,
                     WPT, WTT, BP, BT, MF, MB);

  Ptr3 xs; xs.p[0] = q_in; xs.p[1] = k_in; xs.p[2] = v_in;
  Ptr3 nullp; nullp.p[0] = nullp.p[1] = nullp.p[2] = nullptr;

  // proj q,k,v: fp32 A (cast fused) @ WPT^T + b -> leaky -> H3   [64x128 tiles, dbuf]
  hipLaunchKernelGGL((k_gemmP<1, bf16_t>), dim3(2, Mrows / 64, 3), dim3(256), 0, stream,
                     xs, (const bf16_t*)nullptr, WPT, BP, H3,
                     HID, 0LL, (long long)FAC * HID, (long long)Mrows * FAC, FAC);

  // tran q,k,v: H3 @ WTT^T + b -> q,k into XB; v masked+TRANSPOSED into VTg (k_tv fused)
  hipLaunchKernelGGL((k_gemm<1, bf16_t>), dim3(HID / 128, Mrows / 128, 3), dim3(256), 0, stream,
                     H3, WTT, BT, XB, VTg, MF,
                     HID, FAC, (long long)Mrows * FAC, (long long)FAC * HID, (long long)Mrows * HID, HID,
                     QSCALE, 1.f);

  // attention -> CV (256 q-rows per block, 8 waves, split-KV teams)
  hipLaunchKernelGGL(k_attn, dim3(Ssz / 256, NH, Bsz), dim3(512), 0, stream, XB, MB, CV);

  // proj o: CV @ WPT[o]^T + b -> leaky -> H3[0]   [64x128 tiles, dbuf]
  hipLaunchKernelGGL((k_gemmP<0, bf16_t>), dim3(2, Mrows / 64, 1), dim3(256), 0, stream,
                     nullp, CV, WPT + (size_t)3 * FAC * HID, BP + 3 * FAC, H3,
                     HID, 0LL, 0LL, 0LL, 0);

  // tran o: H3 @ WTT[o]^T + b -> d_out (fp32)
  hipLaunchKernelGGL((k_gemm<0, float>), dim3(HID / 128, Mrows / 128, 1), dim3(256), 0, stream,
                     H3, WTT + (size_t)3 * FAC * HID, BT + 3 * HID, (float*)d_out, (bf16_t*)nullptr,
                     (const float*)nullptr, HID, FAC, 0LL, 0LL, 0LL, 0, 1.f, 1.f);
}

// Round 3
// 343.707 us; speedup vs baseline: 1.9085x; 1.9085x over previous
//
#include <hip/hip_runtime.h>
#include <cstdint>
#include <cstddef>

typedef __bf16 bf16_t;
typedef __bf16 bf16x8 __attribute__((ext_vector_type(8)));
typedef float  f32x4  __attribute__((ext_vector_type(4)));
typedef unsigned int uint32x4 __attribute__((ext_vector_type(4)));
typedef unsigned int uint32x2 __attribute__((ext_vector_type(2)));

#define DEV_INLINE __device__ __forceinline__

constexpr int Bsz = 4, Ssz = 2048, HID = 1024, FAC = 256, NH = 16, DKc = 64;
constexpr int Mrows = Bsz * Ssz; // 8192
constexpr float QSCALE = 0.18033688011112042f; // (1/sqrt(64)) * log2(e)

struct Ptr8 { const float* p[8]; };
struct Ptr3 { const float* p[3]; };

DEV_INLINE float fast_exp2(float x) {
#if __has_builtin(__builtin_amdgcn_exp2f)
  return __builtin_amdgcn_exp2f(x);
#else
  return exp2f(x);
#endif
}

// async global->LDS, 16 B per lane. LDS dest is wave-uniform base + lane*16.
DEV_INLINE void async16(const void* g, void* l) {
  __builtin_amdgcn_global_load_lds((const __attribute__((address_space(1))) void*)g,
                                   (__attribute__((address_space(3))) void*)l, 16, 0, 0);
}

// bank swizzle for [64][64] bf16 tiles staged by global_load_lds:
// LDS[row][c'] holds logical col16 (c' ^ SW(row)). Readers XOR too.
DEV_INLINE int SW(int r) { return (r & 3) | ((r >> 1) & 4); }

// ---------------- prep: weight transpose+cast (z<8) + bias/mask pack (z==8) ----------------
__global__ __launch_bounds__(256) void k_prep(Ptr8 w, Ptr8 bsrc, const int* __restrict__ mask,
                                              bf16_t* wpt, bf16_t* wtt,
                                              float* bp, float* bt, float* mf, bf16_t* mb) {
  const int z = blockIdx.z;
  if (z == 8) {
    const int bid = blockIdx.y * 32 + blockIdx.x;
    if (bid >= 64) return;
    const int i = bid * 256 + threadIdx.x; // 0..16383
    if (i < 4 * FAC) bp[i] = bsrc.p[i >> 8][i & 255];
    if (i < 4 * HID) bt[i] = bsrc.p[4 + (i >> 10)][i & 1023];
    if (i < Bsz * Ssz) {
      const float m = (mask[i] != 0) ? 1.f : 0.f;
      mf[i] = m;
      mb[i] = (bf16_t)m;
    }
    return;
  }
  const int K = (z < 4) ? HID : FAC;
  const int N = (z < 4) ? FAC : HID;
  if ((int)(blockIdx.x * 32) >= N || (int)(blockIdx.y * 32) >= K) return;
  __shared__ float t[32][33];
  const float* src = w.p[z];
  bf16_t* dst = (z < 4) ? (wpt + (size_t)z * FAC * HID) : (wtt + (size_t)(z - 4) * FAC * HID);
  const int tx = threadIdx.x & 31, ty = threadIdx.x >> 5;
  const int kb = blockIdx.y * 32, nb = blockIdx.x * 32;
#pragma unroll
  for (int j = 0; j < 4; ++j)
    t[ty + j * 8][tx] = src[(size_t)(kb + ty + j * 8) * N + nb + tx];
  __syncthreads();
#pragma unroll
  for (int j = 0; j < 4; ++j)
    dst[(size_t)(nb + ty + j * 8) * K + kb + tx] = (bf16_t)t[tx][ty + j * 8];
}

// ---------------- fused factored linear: OUT[M,1024] = (leaky(A@Wp+bp))@Wt + bt ----------------
// Per block: 64 rows. Phase 1: H[64][256] (bf16, LDS, pad 264) = leaky(A[64,1024]@Wp^T+bp).
// Phase 2: OUT[64][1024] = H@Wt^T+bt in 4 chunks of 256 cols, K=256, dbuf staging.
// Epilogues: z=0 q (scale), z=1 k, z=2 v (mask + transpose into [b,h,d,s]), z=3 o (fp32 out).
// 8 waves, 75 KB LDS -> 2 blocks/CU -> 4 waves/SIMD. Hot regs: acc[4][2]+af[4]+bfr[2] ~56.
template <int CAST_A, int QKV, typename OUT_T>
__global__ __launch_bounds__(512, 4) void k_fact(Ptr3 Asrc, const bf16_t* __restrict__ Abf,
                                                 const bf16_t* __restrict__ WpAll,
                                                 const float* __restrict__ bpAll,
                                                 const bf16_t* __restrict__ WtAll,
                                                 const float* __restrict__ btAll,
                                                 OUT_T* __restrict__ CoutAll,
                                                 bf16_t* __restrict__ C2,
                                                 const float* __restrict__ rowmul) {
  constexpr int LDTA = CAST_A ? 40 : 32;
  // smem carve: [phase1: As 2x64x40 | Bs1 2x256x32] aliased by [phase2: Bs2 2x256x32]; H separate.
  __shared__ __align__(16) bf16_t smem[2 * 64 * 40 + 2 * 256 * 32 + 64 * 264];
  bf16_t* As  = smem;                            // phase1 A stage, 2 bufs [64*LDTA]
  bf16_t* Bs1 = smem + 2 * 64 * 40;              // phase1 B stage, 2 bufs [256*32]
  bf16_t* Bs2 = smem;                            // phase2 B stage, 2 bufs [256*32] (aliases)
  bf16_t* Hl  = smem + 2 * 64 * 40 + 2 * 256 * 32; // H [64][264]

  const int z = QKV ? blockIdx.z : 3;
  const bf16_t* Wp = WpAll + (size_t)z * FAC * HID;
  const float* bp = bpAll + z * FAC;
  const bf16_t* Wt = WtAll + (size_t)z * FAC * HID;
  const float* bt = btAll + z * HID;
  OUT_T* Cout = QKV ? (CoutAll + (size_t)blockIdx.z * Mrows * HID) : CoutAll;

  const int tid = threadIdx.x;
  const int lane = tid & 63, wave = tid >> 6; // 0..7
  const int quad = lane >> 4, l16 = lane & 15;
  const int m0 = blockIdx.x * 64;

  // ---- phase 1 staging addresses ----
  // Wp^T tile: 256 rows x 32 k per iter; wave stages rows [wave*32, wave*32+32)
  const int b1row = wave * 32 + (lane >> 2), b1col = (lane & 3) * 8;
  const bf16_t* gW0 = Wp + (size_t)b1row * HID + b1col;
  const bf16_t* gW1 = gW0 + (size_t)16 * HID;
  bf16_t* lW0 = Bs1 + wave * 1024; // 32 rows x 32 = 1024 elems
  bf16_t* lW1 = lW0 + 512;

  const int ar = tid >> 3, acf = (tid & 7) * 4; // cast path: row 0..63, col-f32 0..28
  const float* gAf = nullptr;
  const bf16_t* gAb = nullptr;
  bf16_t* lA = As + wave * 512; // no-cast path (waves 0..3): 16 rows x 32
  if (CAST_A) gAf = Asrc.p[z] + (size_t)(m0 + ar) * HID + acf;
  else        gAb = Abf + (size_t)(m0 + wave * 16 + (lane >> 2)) * HID + (lane & 3) * 8;

  // prologue: stage k0=0 into buffer 0
  async16(gW0, lW0);
  async16(gW1, lW1);
  if (CAST_A) {
    f32x4 x = *(const f32x4*)gAf;
    union { bf16_t h[4]; uint32x2 u; } o;
#pragma unroll
    for (int j = 0; j < 4; ++j) o.h[j] = (bf16_t)x[j];
    *(uint32x2*)(As + ar * LDTA + acf) = o.u;
  } else if (wave < 4) {
    async16(gAb, lA);
  }

  f32x4 acc[4][2] = {};

  for (int it = 0; it < 32; ++it) {
    const int cur = it & 1, nxt = cur ^ 1;
    __syncthreads();

    f32x4 xa = {};
    if (it + 1 < 32) {
      const int k1 = (it + 1) * 32;
      async16(gW0 + k1, lW0 + nxt * 8192);
      async16(gW1 + k1, lW1 + nxt * 8192);
      if (CAST_A) xa = *(const f32x4*)(gAf + k1);
      else if (wave < 4) async16(gAb + k1, lA + nxt * 2048);
    }

    bf16x8 af[4], bfr[2];
#pragma unroll
    for (int i = 0; i < 4; ++i)
      af[i] = *(const bf16x8*)(As + cur * 64 * LDTA + (i * 16 + l16) * LDTA + quad * 8);
#pragma unroll
    for (int i = 0; i < 2; ++i)
      bfr[i] = *(const bf16x8*)(Bs1 + cur * 8192 + (wave * 32 + i * 16 + l16) * 32 + quad * 8);
#pragma unroll
    for (int mi = 0; mi < 4; ++mi)
#pragma unroll
      for (int ni = 0; ni < 2; ++ni)
        acc[mi][ni] = __builtin_amdgcn_mfma_f32_16x16x32_bf16(af[mi], bfr[ni], acc[mi][ni], 0, 0, 0);

    if (CAST_A && it + 1 < 32) {
      union { bf16_t h[4]; uint32x2 u; } o;
#pragma unroll
      for (int j = 0; j < 4; ++j) o.h[j] = (bf16_t)xa[j];
      *(uint32x2*)(As + nxt * 64 * LDTA + ar * LDTA + acf) = o.u;
    }
  }

  // ---- phase 1 epilogue: bias + leaky -> H (LDS) ----
#pragma unroll
  for (int mi = 0; mi < 4; ++mi)
#pragma unroll
    for (int ni = 0; ni < 2; ++ni) {
      const int col = wave * 32 + ni * 16 + l16;
      const float bv = bp[col];
#pragma unroll
      for (int r = 0; r < 4; ++r) {
        float y = acc[mi][ni][r] + bv;
        y = (y > 0.f) ? y : 0.2f * y;
        Hl[(mi * 16 + quad * 4 + r) * 264 + col] = (bf16_t)y;
      }
      acc[mi][ni] = (f32x4){0.f, 0.f, 0.f, 0.f};
    }
  __syncthreads(); // H visible; phase-1 staging region free

  // ---- phase 2: OUT = H @ Wt^T + bt, 4 chunks x 8 k-iters, dbuf ----
  const int b2row = wave * 32 + (lane >> 2), b2col = (lane & 3) * 8;
  // stage chunk tile: Wt rows [nbase, nbase+256) x k [k0, k0+32)
#define STAGE2(ci, buf)                                                                  \
  {                                                                                      \
    const int nb_ = ((ci) >> 3) * 256, k0_ = ((ci) & 7) * 32;                            \
    const bf16_t* g0_ = Wt + (size_t)(nb_ + b2row) * FAC + k0_ + b2col;                  \
    async16(g0_, Bs2 + (buf) * 8192 + wave * 1024);                                      \
    async16(g0_ + 16 * FAC, Bs2 + (buf) * 8192 + wave * 1024 + 512);                     \
  }
  STAGE2(0, 0);

  for (int ci = 0; ci < 32; ++ci) {
    const int cur = ci & 1, nxt = cur ^ 1;
    __syncthreads();
    if (ci + 1 < 32) STAGE2(ci + 1, nxt);

    bf16x8 af[4], bfr[2];
    const int k0 = (ci & 7) * 32;
#pragma unroll
    for (int i = 0; i < 4; ++i)
      af[i] = *(const bf16x8*)(Hl + (i * 16 + l16) * 264 + k0 + quad * 8);
#pragma unroll
    for (int i = 0; i < 2; ++i)
      bfr[i] = *(const bf16x8*)(Bs2 + cur * 8192 + (wave * 32 + i * 16 + l16) * 32 + quad * 8);
#pragma unroll
    for (int mi = 0; mi < 4; ++mi)
#pragma unroll
      for (int ni = 0; ni < 2; ++ni)
        acc[mi][ni] = __builtin_amdgcn_mfma_f32_16x16x32_bf16(af[mi], bfr[ni], acc[mi][ni], 0, 0, 0);

    if ((ci & 7) == 7) {
      const int nbase = (ci >> 3) * 256;
      if (QKV && blockIdx.z == 2) {
        // v: transposed masked write V^T[(b*NH+h)*64+d][s] = (acc+bt)*mask[s]
#pragma unroll
        for (int mi = 0; mi < 4; ++mi) {
          const int rbase = m0 + mi * 16 + quad * 4;
          const int bb = rbase >> 11, s = rbase & 2047;
          float rmv[4];
#pragma unroll
          for (int r = 0; r < 4; ++r) rmv[r] = rowmul[rbase + r];
#pragma unroll
          for (int ni = 0; ni < 2; ++ni) {
            const int col = nbase + wave * 32 + ni * 16 + l16;
            const float bv = bt[col];
            const int hh = col >> 6, d = col & 63;
            union { bf16_t e[4]; uint32x2 u; } p;
#pragma unroll
            for (int r = 0; r < 4; ++r) p.e[r] = (bf16_t)((acc[mi][ni][r] + bv) * rmv[r]);
            *(uint32x2*)(C2 + (((size_t)((bb * NH + hh) * DKc + d)) << 11) + s) = p.u;
          }
        }
      } else {
        const float scale = (QKV && blockIdx.z == 0) ? QSCALE : 1.f;
#pragma unroll
        for (int mi = 0; mi < 4; ++mi) {
          const int row = m0 + mi * 16 + quad * 4;
#pragma unroll
          for (int ni = 0; ni < 2; ++ni) {
            const int col = nbase + wave * 32 + ni * 16 + l16;
            const float bv = bt[col];
#pragma unroll
            for (int r = 0; r < 4; ++r)
              Cout[(size_t)(row + r) * HID + col] = (OUT_T)((acc[mi][ni][r] + bv) * scale);
          }
        }
      }
#pragma unroll
      for (int mi = 0; mi < 4; ++mi)
#pragma unroll
        for (int ni = 0; ni < 2; ++ni) acc[mi][ni] = (f32x4){0.f, 0.f, 0.f, 0.f};
    }
  }
#undef STAGE2
}

// ---------------- flash attention v6: 256 q-rows/block, 8 waves x 2 q-groups ----------------
// Known-good from round 1: 88 us, VGPR 60, 4 waves/SIMD.
__global__ __launch_bounds__(512, 4) void k_attn(const bf16_t* __restrict__ qkv,
                                                 const bf16_t* __restrict__ mb,
                                                 bf16_t* __restrict__ cv) {
  __shared__ __align__(16) bf16_t Ks[2][64 * 64];
  __shared__ __align__(16) bf16_t Vt[2][64 * 64];
  __shared__ __align__(16) bf16_t Ml[Ssz];

  const int qt = blockIdx.x, h = blockIdx.y, b = blockIdx.z;
  const bf16_t* qp = qkv;
  const bf16_t* kp = qkv + (size_t)Mrows * HID;
  const bf16_t* vtp = qkv + 2 * (size_t)Mrows * HID + (size_t)(b * NH + h) * DKc * Ssz;

  const int tid = threadIdx.x;
  const int lane = tid & 63, wave = tid >> 6;   // wave 0..7
  const int quad = lane >> 4, l16 = lane & 15;

  // staging: each of 8 waves stages 8 rows of K and 8 rows of V^T (1024 B each)
  const int r0 = wave * 8 + (lane >> 3);
  const int c0 = ((lane & 7) ^ SW(r0)) * 8;
  const int ldsOff = wave * 512; // elements (1024 B per wave)
  const bf16_t* kgA = kp + (size_t)(b * Ssz + r0) * HID + h * DKc + c0;
  const bf16_t* vgA = vtp + (size_t)r0 * Ssz + c0;

  *(uint32x2*)(Ml + tid * 4) = *(const uint32x2*)(mb + (size_t)b * Ssz + tid * 4);
  async16(kgA, Ks[0] + ldsOff);
  async16(vgA, Vt[0] + ldsOff);

  bf16x8 aq0[2], aq1[2];
#pragma unroll
  for (int g = 0; g < 2; ++g) {
    const size_t qrow = (size_t)(b * Ssz + qt * 256 + g * 128 + wave * 16 + l16) * HID + h * DKc + quad * 8;
    aq0[g] = *(const bf16x8*)(qp + qrow);
    aq1[g] = *(const bf16x8*)(qp + qrow + 32);
  }
  __syncthreads();

  const int krow = 8 * (l16 >> 2) + (l16 & 3);
  f32x4 acc[2][4] = {};
  f32x4 dacc[2] = {};
  const bf16x8 zfrag = {};

  for (int kt = 0; kt < 32; ++kt) {
    const int cur = kt & 1, nxt = cur ^ 1;
    if (kt < 31) {
      const size_t ko = (size_t)(kt + 1) * 64 * HID;
      const int vo = (kt + 1) * 64;
      async16(kgA + ko, Ks[nxt] + ldsOff);
      async16(vgA + vo, Vt[nxt] + ldsOff);
    }

    union U { uint32x4 u; bf16x8 h; } ap0[2], ap1[2];
    constexpr int koff[4] = {0, 4, 32, 36};
#pragma unroll
    for (int ks = 0; ks < 4; ++ks) {
      const int row = krow + koff[ks];
      const int sw = SW(row);
      bf16x8 a0 = *(const bf16x8*)(Ks[cur] + row * 64 + (quad ^ sw) * 8);
      bf16x8 a1 = *(const bf16x8*)(Ks[cur] + row * 64 + ((quad + 4) ^ sw) * 8);
#pragma unroll
      for (int g = 0; g < 2; ++g) {
        f32x4 c = {};
        c = __builtin_amdgcn_mfma_f32_16x16x32_bf16(a0, aq0[g], c, 0, 0, 0);
        c = __builtin_amdgcn_mfma_f32_16x16x32_bf16(a1, aq1[g], c, 0, 0, 0);
        union { bf16_t h[2]; uint32_t u; } p01, p23;
        p01.h[0] = (bf16_t)fast_exp2(c[0]);
        p01.h[1] = (bf16_t)fast_exp2(c[1]);
        p23.h[0] = (bf16_t)fast_exp2(c[2]);
        p23.h[1] = (bf16_t)fast_exp2(c[3]);
        U& t = (ks < 2) ? ap0[g] : ap1[g];
        t.u[(ks & 1) * 2] = p01.u;
        t.u[(ks & 1) * 2 + 1] = p23.u;
      }
    }

    bf16x8 mr0 = *(const bf16x8*)(Ml + kt * 64 + quad * 8);
    bf16x8 mr1 = *(const bf16x8*)(Ml + kt * 64 + 32 + quad * 8);
    if (l16 != 0) { mr0 = zfrag; mr1 = zfrag; }
#pragma unroll
    for (int g = 0; g < 2; ++g) {
      dacc[g] = __builtin_amdgcn_mfma_f32_16x16x32_bf16(ap0[g].h, mr0, dacc[g], 0, 0, 0);
      dacc[g] = __builtin_amdgcn_mfma_f32_16x16x32_bf16(ap1[g].h, mr1, dacc[g], 0, 0, 0);
    }

#pragma unroll
    for (int d = 0; d < 4; ++d) {
      const int row = d * 16 + l16;
      const int sw = SW(row);
      bf16x8 bv0 = *(const bf16x8*)(Vt[cur] + row * 64 + (quad ^ sw) * 8);
      bf16x8 bv1 = *(const bf16x8*)(Vt[cur] + row * 64 + ((quad + 4) ^ sw) * 8);
#pragma unroll
      for (int g = 0; g < 2; ++g) {
        acc[g][d] = __builtin_amdgcn_mfma_f32_16x16x32_bf16(ap0[g].h, bv0, acc[g][d], 0, 0, 0);
        acc[g][d] = __builtin_amdgcn_mfma_f32_16x16x32_bf16(ap1[g].h, bv1, acc[g][d], 0, 0, 0);
      }
    }

    __syncthreads();
  }

#pragma unroll
  for (int g = 0; g < 2; ++g) {
    const size_t obase = (size_t)(b * Ssz + qt * 256 + g * 128 + wave * 16 + quad * 4) * HID + h * DKc + l16;
#pragma unroll
    for (int r = 0; r < 4; ++r) {
      const float denom = __shfl(dacc[g][r], lane & 48, 64);
      const float rl = 1.f / denom;
#pragma unroll
      for (int d = 0; d < 4; ++d)
        cv[obase + (size_t)r * HID + d * 16] = (bf16_t)(acc[g][d][r] * rl);
    }
  }
}

// ---------------- host ----------------
extern "C" void kernel_launch(void* const* d_in, const int* in_sizes, int n_in,
                              void* d_out, int out_size, void* d_ws, size_t ws_size,
                              hipStream_t stream) {
  (void)in_sizes; (void)n_in; (void)out_size; (void)ws_size;
  const float* q_in = (const float*)d_in[0];
  const float* k_in = (const float*)d_in[1];
  const float* v_in = (const float*)d_in[2];
  const int* mask = (const int*)d_in[3];

  bf16_t* XB = (bf16_t*)d_ws;                          // 3 slots [8192,1024] bf16: q, k, V^T
  bf16_t* H3 = XB + (size_t)3 * Mrows * HID;           // (unused by fused path; layout kept)
  bf16_t* CV = H3 + (size_t)3 * Mrows * FAC;           // [8192,1024] bf16 (attn out)
  bf16_t* WPT = CV + (size_t)Mrows * HID;              // 4 x [256,1024] bf16
  bf16_t* WTT = WPT + (size_t)4 * FAC * HID;           // 4 x [1024,256] bf16
  float* BP = (float*)(WTT + (size_t)4 * FAC * HID);   // 4 x 256 f32
  float* BT = BP + 4 * FAC;                            // 4 x 1024 f32
  float* MF = BT + 4 * HID;                            // [8192] f32 mask rowmul
  bf16_t* MB = (bf16_t*)(MF + Mrows);                  // [8192] bf16 mask row
  bf16_t* VTg = XB + 2 * (size_t)Mrows * HID;          // V^T slot

  Ptr8 w;
  w.p[0] = (const float*)d_in[4];  w.p[1] = (const float*)d_in[8];
  w.p[2] = (const float*)d_in[12]; w.p[3] = (const float*)d_in[16];
  w.p[4] = (const float*)d_in[6];  w.p[5] = (const float*)d_in[10];
  w.p[6] = (const float*)d_in[14]; w.p[7] = (const float*)d_in[18];
  Ptr8 bs;
  bs.p[0] = (const float*)d_in[5];  bs.p[1] = (const float*)d_in[9];
  bs.p[2] = (const float*)d_in[13]; bs.p[3] = (const float*)d_in[17];
  bs.p[4] = (const float*)d_in[7];  bs.p[5] = (const float*)d_in[11];
  bs.p[6] = (const float*)d_in[15]; bs.p[7] = (const float*)d_in[19];
  hipLaunchKernelGGL(k_prep, dim3(32, 32, 9), dim3(256), 0, stream, w, bs, mask,
                     WPT, WTT, BP, BT, MF, MB);

  Ptr3 xs; xs.p[0] = q_in; xs.p[1] = k_in; xs.p[2] = v_in;
  Ptr3 nullp; nullp.p[0] = nullp.p[1] = nullp.p[2] = nullptr;

  // fused proj->tran for q,k,v: q (scaled), k -> XB; v masked+TRANSPOSED -> VTg
  hipLaunchKernelGGL((k_fact<1, 1, bf16_t>), dim3(Mrows / 64, 1, 3), dim3(512), 0, stream,
                     xs, (const bf16_t*)nullptr, WPT, BP, WTT, BT, XB, VTg, MF);

  // attention -> CV (256 q-rows per block, 8 waves)
  hipLaunchKernelGGL(k_attn, dim3(Ssz / 256, NH, Bsz), dim3(512), 0, stream, XB, MB, CV);

  // fused proj->tran for o: CV -> d_out (fp32)
  hipLaunchKernelGGL((k_fact<0, 0, float>), dim3(Mrows / 64, 1, 1), dim3(512), 0, stream,
                     nullp, CV, WPT, BP, WTT, BT, (float*)d_out, (bf16_t*)nullptr,
                     (const float*)nullptr);
}

// Round 4
// 335.332 us; speedup vs baseline: 1.9562x; 1.0250x over previous
//
#include <hip/hip_runtime.h>
#include <cstdint>
#include <cstddef>

typedef __bf16 bf16_t;
typedef __bf16 bf16x8 __attribute__((ext_vector_type(8)));
typedef float  f32x4  __attribute__((ext_vector_type(4)));
typedef unsigned int uint32x4 __attribute__((ext_vector_type(4)));
typedef unsigned int uint32x2 __attribute__((ext_vector_type(2)));

#define DEV_INLINE __device__ __forceinline__

constexpr int Bsz = 4, Ssz = 2048, HID = 1024, FAC = 256, NH = 16, DKc = 64;
constexpr int Mrows = Bsz * Ssz; // 8192
constexpr float QSCALE = 0.18033688011112042f; // (1/sqrt(64)) * log2(e)

struct Ptr8 { const float* p[8]; };
struct Ptr3 { const float* p[3]; };

DEV_INLINE float fast_exp2(float x) {
#if __has_builtin(__builtin_amdgcn_exp2f)
  return __builtin_amdgcn_exp2f(x);
#else
  return exp2f(x);
#endif
}

// async global->LDS, 16 B per lane. LDS dest is wave-uniform base + lane*16.
DEV_INLINE void async16(const void* g, void* l) {
  __builtin_amdgcn_global_load_lds((const __attribute__((address_space(1))) void*)g,
                                   (__attribute__((address_space(3))) void*)l, 16, 0, 0);
}

// Counted-vmcnt barrier: wait until only the N newest VMEM ops remain in flight,
// drain LDS ops (for ds_write visibility), then RAW barrier (no implicit drain).
#define WBAR(N) do { \
  asm volatile("s_waitcnt vmcnt(" #N ") lgkmcnt(0)" ::: "memory"); \
  __builtin_amdgcn_s_barrier(); \
} while (0)

// bank swizzle for [64][64] bf16 tiles staged by global_load_lds:
// LDS[row][c'] holds logical col16 (c' ^ SW(row)). Readers XOR too.
DEV_INLINE int SW(int r) { return (r & 3) | ((r >> 1) & 4); }

// ---------------- prep: weight transpose+cast (z<8) + bias/mask pack (z==8) ----------------
__global__ __launch_bounds__(256) void k_prep(Ptr8 w, Ptr8 bsrc, const int* __restrict__ mask,
                                              bf16_t* wpt, bf16_t* wtt,
                                              float* bp, float* bt, float* mf, bf16_t* mb) {
  const int z = blockIdx.z;
  if (z == 8) {
    const int bid = blockIdx.y * 32 + blockIdx.x;
    if (bid >= 64) return;
    const int i = bid * 256 + threadIdx.x; // 0..16383
    if (i < 4 * FAC) bp[i] = bsrc.p[i >> 8][i & 255];
    if (i < 4 * HID) bt[i] = bsrc.p[4 + (i >> 10)][i & 1023];
    if (i < Bsz * Ssz) {
      const float m = (mask[i] != 0) ? 1.f : 0.f;
      mf[i] = m;
      mb[i] = (bf16_t)m;
    }
    return;
  }
  const int K = (z < 4) ? HID : FAC;
  const int N = (z < 4) ? FAC : HID;
  if ((int)(blockIdx.x * 32) >= N || (int)(blockIdx.y * 32) >= K) return;
  __shared__ float t[32][33];
  const float* src = w.p[z];
  bf16_t* dst = (z < 4) ? (wpt + (size_t)z * FAC * HID) : (wtt + (size_t)(z - 4) * FAC * HID);
  const int tx = threadIdx.x & 31, ty = threadIdx.x >> 5;
  const int kb = blockIdx.y * 32, nb = blockIdx.x * 32;
#pragma unroll
  for (int j = 0; j < 4; ++j)
    t[ty + j * 8][tx] = src[(size_t)(kb + ty + j * 8) * N + nb + tx];
  __syncthreads();
#pragma unroll
  for (int j = 0; j < 4; ++j)
    dst[(size_t)(nb + ty + j * 8) * K + kb + tx] = (bf16_t)t[tx][ty + j * 8];
}

// ---------------- proj GEMM (qkv): C[M,256] = leaky(A_f32[M,1024] @ Bt[256,1024]^T + bias) ----------------
// 64x128 tile, 4 waves, BK=32, nk=32. Counted-vmcnt pipeline:
//  - A (fp32->bf16 cast) register-staged, LDS TRIPLE buffered (write it+1 while reads span it-1,it).
//  - B async16-staged, QUAD buffered, prefetch distance 2.
//  - Per-iter VMEM order: [A-reg loads for it+1][B async for it+2]; A-LDS-write after MFMAs
//    waits only the A loads (B async stay in flight). WBAR(6) keeps {B(it+1)^2, xa,xb, B(it+2)^2}.
__global__ __launch_bounds__(256, 2) void k_gemmP2(Ptr3 Asrc,
                                                   const bf16_t* __restrict__ Bt_,
                                                   const float* __restrict__ biasAll,
                                                   bf16_t* __restrict__ Call) {
  __shared__ __align__(16) bf16_t As[3][64 * 40];
  __shared__ __align__(16) bf16_t Bs[4][128 * 32];

  const int z = blockIdx.z;
  const bf16_t* Bt = Bt_ + (size_t)z * FAC * HID;
  const float* bias = biasAll + z * FAC;
  bf16_t* C = Call + (size_t)z * Mrows * FAC;

  const int tid = threadIdx.x;
  const int lane = tid & 63, wave = tid >> 6;
  const int quad = lane >> 4, l16 = lane & 15;
  const int m0 = blockIdx.y * 64, n0 = blockIdx.x * 128;

  const int brow = wave * 16 + (lane >> 2), bkc = (lane & 3) * 8;
  const bf16_t* gB0 = Bt + (size_t)(n0 + brow) * HID + bkc;
  const bf16_t* gB1 = gB0 + (size_t)64 * HID;

  const int crow = tid >> 2, chalf = (tid & 3) * 8;
  const float* gAf = Asrc.p[z] + (size_t)(m0 + crow) * HID + chalf;

#define ASYNCB(t, buf)                                \
  do {                                                \
    const int k0_ = (t) * 32;                         \
    async16(gB0 + k0_, Bs[buf] + wave * 512);         \
    async16(gB1 + k0_, Bs[buf] + 2048 + wave * 512);  \
  } while (0)

  // prologue: A(0) regs first, then B(0),B(1) asyncs, then A(0) LDS write.
  {
    f32x4 pa = *(const f32x4*)gAf;
    f32x4 pb = *(const f32x4*)(gAf + 4);
    __builtin_amdgcn_sched_barrier(0);
    ASYNCB(0, 0);
    ASYNCB(1, 1);
    union { bf16_t h[8]; uint32x4 u; } o;
#pragma unroll
    for (int j = 0; j < 4; ++j) { o.h[j] = (bf16_t)pa[j]; o.h[4 + j] = (bf16_t)pb[j]; }
    *(uint32x4*)(As[0] + crow * 40 + chalf) = o.u;
  }

  f32x4 acc[4][2] = {};
  constexpr int nk = 32;

  for (int it = 0; it < nk; ++it) {
    f32x4 xa, xb;
    const int k1 = (it + 1) * 32;
    if (it + 1 < nk) {
      xa = *(const f32x4*)(gAf + k1);
      xb = *(const f32x4*)(gAf + k1 + 4);
    }
    __builtin_amdgcn_sched_barrier(0);
    if (it + 2 < nk) ASYNCB(it + 2, (it + 2) & 3);

    if (it + 2 < nk)      WBAR(6);
    else if (it + 1 < nk) WBAR(4);
    else                  WBAR(0);

    const bf16_t* Ac = As[it % 3];
    const bf16_t* Bc = Bs[it & 3];
    bf16x8 af[4], bfr[2];
#pragma unroll
    for (int i = 0; i < 4; ++i)
      af[i] = *(const bf16x8*)(Ac + (i * 16 + l16) * 40 + quad * 8);
#pragma unroll
    for (int i = 0; i < 2; ++i)
      bfr[i] = *(const bf16x8*)(Bc + (wave * 32 + i * 16 + l16) * 32 + quad * 8);
#pragma unroll
    for (int mi = 0; mi < 4; ++mi)
#pragma unroll
      for (int ni = 0; ni < 2; ++ni)
        acc[mi][ni] = __builtin_amdgcn_mfma_f32_16x16x32_bf16(af[mi], bfr[ni], acc[mi][ni], 0, 0, 0);

    if (it + 1 < nk) {
      union { bf16_t h[8]; uint32x4 u; } o;
#pragma unroll
      for (int j = 0; j < 4; ++j) { o.h[j] = (bf16_t)xa[j]; o.h[4 + j] = (bf16_t)xb[j]; }
      *(uint32x4*)(As[(it + 1) % 3] + crow * 40 + chalf) = o.u;
    }
  }
#undef ASYNCB

#pragma unroll
  for (int mi = 0; mi < 4; ++mi) {
    const int rbase = m0 + mi * 16 + quad * 4;
#pragma unroll
    for (int ni = 0; ni < 2; ++ni) {
      const int col = n0 + wave * 32 + ni * 16 + l16;
      const float bv = bias[col];
#pragma unroll
      for (int r = 0; r < 4; ++r) {
        float y = acc[mi][ni][r] + bv;
        y = (y > 0.f) ? y : 0.2f * y;
        C[(size_t)(rbase + r) * FAC + col] = (bf16_t)y;
      }
    }
  }
}

// ---------------- quad-buffered GEMM: C[M,N] = f(A[M,K] @ Bt[N,K]^T + bias) ----------------
// 128x128 tile, 4 waves (each 64x64), BK=32, pure async16 staging, QUAD buffer, WBAR(8/4/0).
// EPI: 0 = leaky->bf16 (proj, C stride N); 1 = tran-qkv (z0 scale QSCALE, z1 1.0, z2 mask+transpose
// into C2 [b,h,d,s]); 2 = fp32 out (tran o).
template <int EPI, typename OUT_T>
__global__ __launch_bounds__(256, 2) void k_gemmQ(const bf16_t* __restrict__ Aall,
                                                  const bf16_t* __restrict__ Btall,
                                                  const float* __restrict__ biasAll,
                                                  OUT_T* __restrict__ Call,
                                                  bf16_t* __restrict__ C2,
                                                  const float* __restrict__ rowmul,
                                                  int N, int K,
                                                  long long Az, long long Bz, long long Cz, int biasz) {
  __shared__ __align__(16) bf16_t As[4][128 * 32];
  __shared__ __align__(16) bf16_t Bs[4][128 * 32];

  const int z = blockIdx.z;
  const bf16_t* Bt = Btall + (size_t)z * Bz;
  const float* bias = biasAll + (size_t)z * biasz;
  OUT_T* C = Call + (size_t)z * Cz;

  const int tid = threadIdx.x;
  const int lane = tid & 63, wave = tid >> 6;
  const int quad = lane >> 4, l16 = lane & 15;
  const int wr = wave >> 1, wc = wave & 1;
  const int m0 = blockIdx.y * 128, n0 = blockIdx.x * 128;

  const int arow = wave * 16 + (lane >> 2), akc = (lane & 3) * 8;
  const bf16_t* gB0 = Bt + (size_t)(n0 + arow) * K + akc;
  const bf16_t* gB1 = gB0 + (size_t)64 * K;
  const bf16_t* A = Aall + (size_t)z * Az;
  const bf16_t* gA0 = A + (size_t)(m0 + arow) * K + akc;
  const bf16_t* gA1 = gA0 + (size_t)64 * K;

#define STAGEQ(t, buf)                               \
  do {                                               \
    const int k0_ = (t) * 32;                        \
    async16(gA0 + k0_, As[buf] + wave * 512);        \
    async16(gA1 + k0_, As[buf] + 2048 + wave * 512); \
    async16(gB0 + k0_, Bs[buf] + wave * 512);        \
    async16(gB1 + k0_, Bs[buf] + 2048 + wave * 512); \
  } while (0)

  const int nk = K / 32;
  STAGEQ(0, 0);
  STAGEQ(1, 1);

  f32x4 acc[4][4] = {};

  for (int it = 0; it < nk; ++it) {
    if (it + 2 < nk) STAGEQ(it + 2, (it + 2) & 3);

    if (it + 2 < nk)      WBAR(8);
    else if (it + 1 < nk) WBAR(4);
    else                  WBAR(0);

    const bf16_t* Ac = As[it & 3];
    const bf16_t* Bc = Bs[it & 3];
    bf16x8 af[4], bfr[4];
#pragma unroll
    for (int i = 0; i < 4; ++i)
      af[i] = *(const bf16x8*)(Ac + (wr * 64 + i * 16 + l16) * 32 + quad * 8);
#pragma unroll
    for (int i = 0; i < 4; ++i)
      bfr[i] = *(const bf16x8*)(Bc + (wc * 64 + i * 16 + l16) * 32 + quad * 8);
#pragma unroll
    for (int mi = 0; mi < 4; ++mi)
#pragma unroll
      for (int ni = 0; ni < 4; ++ni)
        acc[mi][ni] = __builtin_amdgcn_mfma_f32_16x16x32_bf16(af[mi], bfr[ni], acc[mi][ni], 0, 0, 0);
  }
#undef STAGEQ

  if (EPI == 1 && z == 2) {
    // transposed masked write: V^T[(b*NH+h)*64+d][s] = (acc + bias) * mask[s]
#pragma unroll
    for (int mi = 0; mi < 4; ++mi) {
      const int rbase = m0 + wr * 64 + mi * 16 + quad * 4;
      const int bb = rbase >> 11, s = rbase & 2047;
      float rmv[4];
#pragma unroll
      for (int r = 0; r < 4; ++r) rmv[r] = rowmul[rbase + r];
#pragma unroll
      for (int ni = 0; ni < 4; ++ni) {
        const int col = n0 + wc * 64 + ni * 16 + l16;
        const float bv = bias[col];
        const int hh = col >> 6, d = col & 63;
        union { bf16_t e[4]; uint32x2 u; } p;
#pragma unroll
        for (int r = 0; r < 4; ++r) p.e[r] = (bf16_t)((acc[mi][ni][r] + bv) * rmv[r]);
        *(uint32x2*)(C2 + (((size_t)((bb * NH + hh) * DKc + d)) << 11) + s) = p.u;
      }
    }
    return;
  }

  const float scale = (EPI == 1 && z == 0) ? QSCALE : 1.f;
#pragma unroll
  for (int mi = 0; mi < 4; ++mi) {
    const int rbase = m0 + wr * 64 + mi * 16 + quad * 4;
#pragma unroll
    for (int ni = 0; ni < 4; ++ni) {
      const int col = n0 + wc * 64 + ni * 16 + l16;
      const float bv = bias[col];
#pragma unroll
      for (int r = 0; r < 4; ++r) {
        float y = (acc[mi][ni][r] + bv) * scale;
        if (EPI == 0) y = (y > 0.f) ? y : 0.2f * y;
        C[(size_t)(rbase + r) * N + col] = (OUT_T)y;
      }
    }
  }
}

// ---------------- flash attention v8: v6 math + quad-buffer + counted vmcnt ----------------
// 256 q-rows/block, 8 waves x 2 q-groups. K/V quad-buffered (68 KB LDS, 2 blocks/CU),
// WBAR(4/2/0) keeps the 2 newest stages (2 async each) in flight across the barrier.
__global__ __launch_bounds__(512, 4) void k_attn(const bf16_t* __restrict__ qkv,
                                                 const bf16_t* __restrict__ mb,
                                                 bf16_t* __restrict__ cv) {
  __shared__ __align__(16) bf16_t Ks[4][64 * 64];
  __shared__ __align__(16) bf16_t Vt[4][64 * 64];
  __shared__ __align__(16) bf16_t Ml[Ssz];

  const int qt = blockIdx.x, h = blockIdx.y, b = blockIdx.z;
  const bf16_t* qp = qkv;
  const bf16_t* kp = qkv + (size_t)Mrows * HID;
  const bf16_t* vtp = qkv + 2 * (size_t)Mrows * HID + (size_t)(b * NH + h) * DKc * Ssz;

  const int tid = threadIdx.x;
  const int lane = tid & 63, wave = tid >> 6;   // wave 0..7
  const int quad = lane >> 4, l16 = lane & 15;

  // staging: each of 8 waves stages 8 rows of K and 8 rows of V^T (1024 B each)
  const int r0 = wave * 8 + (lane >> 3);
  const int c0 = ((lane & 7) ^ SW(r0)) * 8;
  const int ldsOff = wave * 512; // elements (1024 B per wave)
  const bf16_t* kgA = kp + (size_t)(b * Ssz + r0) * HID + h * DKc + c0;
  const bf16_t* vgA = vtp + (size_t)r0 * Ssz + c0;

#define STAGEA(t, buf)                                          \
  do {                                                          \
    async16(kgA + (size_t)(t) * 64 * HID, Ks[buf] + ldsOff);    \
    async16(vgA + (t) * 64, Vt[buf] + ldsOff);                  \
  } while (0)

  *(uint32x2*)(Ml + tid * 4) = *(const uint32x2*)(mb + (size_t)b * Ssz + tid * 4);
  STAGEA(0, 0);
  STAGEA(1, 1);

  bf16x8 aq0[2], aq1[2];
#pragma unroll
  for (int g = 0; g < 2; ++g) {
    const size_t qrow = (size_t)(b * Ssz + qt * 256 + g * 128 + wave * 16 + l16) * HID + h * DKc + quad * 8;
    aq0[g] = *(const bf16x8*)(qp + qrow);
    aq1[g] = *(const bf16x8*)(qp + qrow + 32);
  }

  const int krow = 8 * (l16 >> 2) + (l16 & 3);
  f32x4 acc[2][4] = {};
  f32x4 dacc[2] = {};
  const bf16x8 zfrag = {};

  for (int kt = 0; kt < 32; ++kt) {
    if (kt + 2 < 32) STAGEA(kt + 2, (kt + 2) & 3);

    if (kt + 2 < 32)      WBAR(4);
    else if (kt + 1 < 32) WBAR(2);
    else                  WBAR(0);

    const bf16_t* Kc = Ks[kt & 3];
    const bf16_t* Vc = Vt[kt & 3];

    union U { uint32x4 u; bf16x8 h; } ap0[2], ap1[2];
    constexpr int koff[4] = {0, 4, 32, 36};
#pragma unroll
    for (int ks = 0; ks < 4; ++ks) {
      const int row = krow + koff[ks];
      const int sw = SW(row);
      bf16x8 a0 = *(const bf16x8*)(Kc + row * 64 + (quad ^ sw) * 8);
      bf16x8 a1 = *(const bf16x8*)(Kc + row * 64 + ((quad + 4) ^ sw) * 8);
#pragma unroll
      for (int g = 0; g < 2; ++g) {
        f32x4 c = {};
        c = __builtin_amdgcn_mfma_f32_16x16x32_bf16(a0, aq0[g], c, 0, 0, 0);
        c = __builtin_amdgcn_mfma_f32_16x16x32_bf16(a1, aq1[g], c, 0, 0, 0);
        union { bf16_t h[2]; uint32_t u; } p01, p23;
        p01.h[0] = (bf16_t)fast_exp2(c[0]);
        p01.h[1] = (bf16_t)fast_exp2(c[1]);
        p23.h[0] = (bf16_t)fast_exp2(c[2]);
        p23.h[1] = (bf16_t)fast_exp2(c[3]);
        U& t = (ks < 2) ? ap0[g] : ap1[g];
        t.u[(ks & 1) * 2] = p01.u;
        t.u[(ks & 1) * 2 + 1] = p23.u;
      }
    }

    bf16x8 mr0 = *(const bf16x8*)(Ml + kt * 64 + quad * 8);
    bf16x8 mr1 = *(const bf16x8*)(Ml + kt * 64 + 32 + quad * 8);
    if (l16 != 0) { mr0 = zfrag; mr1 = zfrag; }
#pragma unroll
    for (int g = 0; g < 2; ++g) {
      dacc[g] = __builtin_amdgcn_mfma_f32_16x16x32_bf16(ap0[g].h, mr0, dacc[g], 0, 0, 0);
      dacc[g] = __builtin_amdgcn_mfma_f32_16x16x32_bf16(ap1[g].h, mr1, dacc[g], 0, 0, 0);
    }

#pragma unroll
    for (int d = 0; d < 4; ++d) {
      const int row = d * 16 + l16;
      const int sw = SW(row);
      bf16x8 bv0 = *(const bf16x8*)(Vc + row * 64 + (quad ^ sw) * 8);
      bf16x8 bv1 = *(const bf16x8*)(Vc + row * 64 + ((quad + 4) ^ sw) * 8);
#pragma unroll
      for (int g = 0; g < 2; ++g) {
        acc[g][d] = __builtin_amdgcn_mfma_f32_16x16x32_bf16(ap0[g].h, bv0, acc[g][d], 0, 0, 0);
        acc[g][d] = __builtin_amdgcn_mfma_f32_16x16x32_bf16(ap1[g].h, bv1, acc[g][d], 0, 0, 0);
      }
    }
  }
#undef STAGEA

#pragma unroll
  for (int g = 0; g < 2; ++g) {
    const size_t obase = (size_t)(b * Ssz + qt * 256 + g * 128 + wave * 16 + quad * 4) * HID + h * DKc + l16;
#pragma unroll
    for (int r = 0; r < 4; ++r) {
      const float denom = __shfl(dacc[g][r], lane & 48, 64);
      const float rl = 1.f / denom;
#pragma unroll
      for (int d = 0; d < 4; ++d)
        cv[obase + (size_t)r * HID + d * 16] = (bf16_t)(acc[g][d][r] * rl);
    }
  }
}

// ---------------- host ----------------
extern "C" void kernel_launch(void* const* d_in, const int* in_sizes, int n_in,
                              void* d_out, int out_size, void* d_ws, size_t ws_size,
                              hipStream_t stream) {
  (void)in_sizes; (void)n_in; (void)out_size; (void)ws_size;
  const float* q_in = (const float*)d_in[0];
  const float* k_in = (const float*)d_in[1];
  const float* v_in = (const float*)d_in[2];
  const int* mask = (const int*)d_in[3];

  bf16_t* XB = (bf16_t*)d_ws;                          // 3 slots [8192,1024] bf16: q, k, V^T
  bf16_t* H3 = XB + (size_t)3 * Mrows * HID;           // 3 x [8192,256] bf16
  bf16_t* CV = H3 + (size_t)3 * Mrows * FAC;           // [8192,1024] bf16 (attn out)
  bf16_t* WPT = CV + (size_t)Mrows * HID;              // 4 x [256,1024] bf16
  bf16_t* WTT = WPT + (size_t)4 * FAC * HID;           // 4 x [1024,256] bf16
  float* BP = (float*)(WTT + (size_t)4 * FAC * HID);   // 4 x 256 f32
  float* BT = BP + 4 * FAC;                            // 4 x 1024 f32
  float* MF = BT + 4 * HID;                            // [8192] f32 mask rowmul
  bf16_t* MB = (bf16_t*)(MF + Mrows);                  // [8192] bf16 mask row
  bf16_t* VTg = XB + 2 * (size_t)Mrows * HID;          // V^T slot

  Ptr8 w;
  w.p[0] = (const float*)d_in[4];  w.p[1] = (const float*)d_in[8];
  w.p[2] = (const float*)d_in[12]; w.p[3] = (const float*)d_in[16];
  w.p[4] = (const float*)d_in[6];  w.p[5] = (const float*)d_in[10];
  w.p[6] = (const float*)d_in[14]; w.p[7] = (const float*)d_in[18];
  Ptr8 bs;
  bs.p[0] = (const float*)d_in[5];  bs.p[1] = (const float*)d_in[9];
  bs.p[2] = (const float*)d_in[13]; bs.p[3] = (const float*)d_in[17];
  bs.p[4] = (const float*)d_in[7];  bs.p[5] = (const float*)d_in[11];
  bs.p[6] = (const float*)d_in[15]; bs.p[7] = (const float*)d_in[19];
  hipLaunchKernelGGL(k_prep, dim3(32, 32, 9), dim3(256), 0, stream, w, bs, mask,
                     WPT, WTT, BP, BT, MF, MB);

  Ptr3 xs; xs.p[0] = q_in; xs.p[1] = k_in; xs.p[2] = v_in;

  // proj q,k,v: fp32 A (cast fused) @ WPT^T + b -> leaky -> H3 [counted-vmcnt pipeline]
  hipLaunchKernelGGL(k_gemmP2, dim3(2, Mrows / 64, 3), dim3(256), 0, stream,
                     xs, WPT, BP, H3);

  // tran q,k,v: H3 @ WTT^T + b -> q(scaled),k into XB; v masked+TRANSPOSED into VTg
  hipLaunchKernelGGL((k_gemmQ<1, bf16_t>), dim3(HID / 128, Mrows / 128, 3), dim3(256), 0, stream,
                     H3, WTT, BT, XB, VTg, MF,
                     HID, FAC, (long long)Mrows * FAC, (long long)FAC * HID, (long long)Mrows * HID, HID);

  // attention -> CV (256 q-rows per block, 8 waves, quad-buffer)
  hipLaunchKernelGGL(k_attn, dim3(Ssz / 256, NH, Bsz), dim3(512), 0, stream, XB, MB, CV);

  // proj o: CV @ WPT[o]^T + b -> leaky -> H3[0]
  hipLaunchKernelGGL((k_gemmQ<0, bf16_t>), dim3(FAC / 128, Mrows / 128, 1), dim3(256), 0, stream,
                     CV, WPT + (size_t)3 * FAC * HID, BP + 3 * FAC, H3, (bf16_t*)nullptr,
                     (const float*)nullptr, FAC, HID, 0LL, 0LL, 0LL, 0);

  // tran o: H3 @ WTT[o]^T + b -> d_out (fp32)
  hipLaunchKernelGGL((k_gemmQ<2, float>), dim3(HID / 128, Mrows / 128, 1), dim3(256), 0, stream,
                     H3, WTT + (size_t)3 * FAC * HID, BT + 3 * HID, (float*)d_out, (bf16_t*)nullptr,
                     (const float*)nullptr, HID, FAC, 0LL, 0LL, 0LL, 0);
}